// Round 1
// baseline (309.152 us; speedup 1.0000x reference)
//
#include <hip/hip_runtime.h>

#define Tdim 4096
#define Bdim 8
#define Cdim 64
#define Ldim 15
#define Idim 2048   // T / STRIDE
#define OUTW 4160   // C + C*C

// One block per (b, window i). 256 threads.
//  Phase 1: stage x[s-14 .. s+14][0..63] into LDS (zero-padded).
//  Phase 2: mu[l][c] = sum_k w1[k]*xbuf[l+k][c]; xc[l][c] = in-range ? x - mu : 0.
//  Phase 3: sigma sub-tile per thread: c = jj*16 + (tid>>4), d = (tid&15)*4 + dd.
//           => sigma flat offset = jj*1024 + 4*tid + dd (coalesced float4 stores).
//  Phase 4: block reduce sum(out^2), rsqrt, scale, write.
__global__ __launch_bounds__(256) void cbp_kernel(const float* __restrict__ x,
                                                  const float* __restrict__ w1,
                                                  const float* __restrict__ w2,
                                                  float* __restrict__ out) {
    __shared__ float xbuf[29][64];
    __shared__ float xcs[15][64];
    __shared__ float mus[64];
    __shared__ float w1s[16], w2s[16];
    __shared__ float red[4];
    __shared__ float scale_s;

    const int tid = threadIdx.x;
    const int blk = blockIdx.x;
    const int b = blk >> 11;       // / Idim
    const int i = blk & (Idim - 1);
    const int s = i << 1;          // STRIDE = 2

    if (tid < Ldim) { w1s[tid] = w1[tid]; w2s[tid] = w2[tid]; }

    // ---- Phase 1: load 29 rows (float4-vectorized, zero-padded) ----
    const float* xb = x + (size_t)b * Tdim * Cdim;
    for (int v = tid; v < 29 * 16; v += 256) {
        const int r = v >> 4;
        const int c4 = (v & 15) << 2;
        const int t = s - 14 + r;
        float4 val = make_float4(0.f, 0.f, 0.f, 0.f);
        if (t >= 0 && t < Tdim) val = *(const float4*)(xb + (size_t)t * Cdim + c4);
        *(float4*)(&xbuf[r][c4]) = val;
    }
    __syncthreads();

    // ---- Phase 2: mu + centered xc (15 rows x 16 float4 = 240 tasks) ----
    if (tid < 240) {
        const int l = tid >> 4;
        const int c4 = (tid & 15) << 2;
        const int t = s - 7 + l;
        float4 m = make_float4(0.f, 0.f, 0.f, 0.f);
#pragma unroll
        for (int k = 0; k < Ldim; ++k) {
            const float w = w1s[k];
            const float4 xv = *(const float4*)(&xbuf[l + k][c4]);
            m.x = fmaf(w, xv.x, m.x);
            m.y = fmaf(w, xv.y, m.y);
            m.z = fmaf(w, xv.z, m.z);
            m.w = fmaf(w, xv.w, m.w);
        }
        const float4 xv = *(const float4*)(&xbuf[l + 7][c4]);
        float4 xc;
        if (t >= 0 && t < Tdim) {
            xc = make_float4(xv.x - m.x, xv.y - m.y, xv.z - m.z, xv.w - m.w);
        } else {
            xc = make_float4(0.f, 0.f, 0.f, 0.f);
        }
        *(float4*)(&xcs[l][c4]) = xc;
        if (l == 7) *(float4*)(&mus[c4]) = m;  // mu at t == s (always in range)
    }
    __syncthreads();

    // ---- Phase 3: sigma sub-tile: acc[jj][dd] over c = jj*16+q, d = d0+dd ----
    const int q  = tid >> 4;          // 0..15
    const int d0 = (tid & 15) << 2;   // 0,4,...,60
    float acc[4][4];
#pragma unroll
    for (int jj = 0; jj < 4; ++jj)
#pragma unroll
        for (int dd = 0; dd < 4; ++dd) acc[jj][dd] = 0.f;

#pragma unroll
    for (int l = 0; l < Ldim; ++l) {
        const float4 xd = *(const float4*)(&xcs[l][d0]);   // ds_read_b128
        const float w = w2s[l];
#pragma unroll
        for (int jj = 0; jj < 4; ++jj) {
            const float a = w * xcs[l][jj * 16 + q];       // broadcast read
            acc[jj][0] = fmaf(a, xd.x, acc[jj][0]);
            acc[jj][1] = fmaf(a, xd.y, acc[jj][1]);
            acc[jj][2] = fmaf(a, xd.z, acc[jj][2]);
            acc[jj][3] = fmaf(a, xd.w, acc[jj][3]);
        }
    }

    // ---- Phase 4: sum of squares over the full 4160-row, then scale ----
    float local = 0.f;
#pragma unroll
    for (int jj = 0; jj < 4; ++jj)
#pragma unroll
        for (int dd = 0; dd < 4; ++dd) local = fmaf(acc[jj][dd], acc[jj][dd], local);
    if (tid < Cdim) local = fmaf(mus[tid], mus[tid], local);

#pragma unroll
    for (int off = 32; off; off >>= 1) local += __shfl_down(local, off, 64);
    if ((tid & 63) == 0) red[tid >> 6] = local;
    __syncthreads();
    if (tid == 0) {
        const float ss = red[0] + red[1] + red[2] + red[3];
        scale_s = rsqrtf(fmaxf(ss, 1e-12f));
    }
    __syncthreads();
    const float sc = scale_s;

    float* orow = out + (size_t)blk * OUTW;
    if (tid < 16) {
        float4 m4 = *(const float4*)(&mus[tid << 2]);
        m4.x *= sc; m4.y *= sc; m4.z *= sc; m4.w *= sc;
        *(float4*)(orow + (tid << 2)) = m4;
    }
    float* osig = orow + Cdim;
#pragma unroll
    for (int jj = 0; jj < 4; ++jj) {
        const float4 v = make_float4(acc[jj][0] * sc, acc[jj][1] * sc,
                                     acc[jj][2] * sc, acc[jj][3] * sc);
        *(float4*)(osig + jj * 1024 + (tid << 2)) = v;   // contiguous per wave
    }
}

extern "C" void kernel_launch(void* const* d_in, const int* in_sizes, int n_in,
                              void* d_out, int out_size, void* d_ws, size_t ws_size,
                              hipStream_t stream) {
    const float* x  = (const float*)d_in[0];
    const float* w1 = (const float*)d_in[1];
    const float* w2 = (const float*)d_in[2];
    float* out = (float*)d_out;
    cbp_kernel<<<dim3(Bdim * Idim), dim3(256), 0, stream>>>(x, w1, w2, out);
}

// Round 2
// 289.322 us; speedup vs baseline: 1.0685x; 1.0685x over previous
//
#include <hip/hip_runtime.h>

#define Tdim 4096
#define Bdim 8
#define Cdim 64
#define Ldim 15
#define Idim 2048   // T / STRIDE
#define OUTW 4160   // C + C*C
#define G    4      // windows per block
#define RX   (2*G + 27)   // 35 staged x rows
#define RXC  (2*G + 13)   // 21 centered rows

// One block = G=4 consecutive windows of one batch. 256 threads.
//  P1: stage x[s0-14 .. s0+2(G-1)+14] (35x64) into LDS, zero-padded.
//  P2: compute 21 unique xc rows ONCE (vs 15 per window before); keep mu at
//      the G output positions.
//  P3: per thread: c-tile c0=(tid>>4)*4, d-tile d0=(tid&15)*4. For each of the
//      21 rows read TWO ds_read_b128 and scatter-FMA into every window g with
//      tap l = r-2g in [0,15). 64 fp32 accumulators.
//  P4: per-window sum-of-squares reduce, rsqrt, scaled coalesced stores.
__global__ __launch_bounds__(256, 4) void cbp_kernel(const float* __restrict__ x,
                                                     const float* __restrict__ w1,
                                                     const float* __restrict__ w2,
                                                     float* __restrict__ out) {
    __shared__ float xbuf[RX][64];
    __shared__ float xcs[RXC][64];
    __shared__ float mus[G][64];
    __shared__ float red[4][G];
    __shared__ float scale_s[G];

    const int tid = threadIdx.x;
    const int blk = blockIdx.x;
    const int b  = blk >> 9;            // / (Idim/G = 512)
    const int i0 = (blk & 511) << 2;    // first window index
    const int s0 = i0 << 1;             // STRIDE = 2

    // ---- P1: stage 35 rows, float4, zero-padded ----
    const float* xb = x + (size_t)b * (Tdim * Cdim);
    for (int v = tid; v < RX * 16; v += 256) {
        const int r  = v >> 4;
        const int c4 = (v & 15) << 2;
        const int t  = s0 - 14 + r;
        float4 val = make_float4(0.f, 0.f, 0.f, 0.f);
        if (t >= 0 && t < Tdim) val = *(const float4*)(xb + (size_t)t * Cdim + c4);
        *(float4*)(&xbuf[r][c4]) = val;
    }
    __syncthreads();

    // ---- P2: 21 unique xc rows (336 float4 tasks); mu kept at j=7,9,11,13 ----
    for (int v = tid; v < RXC * 16; v += 256) {
        const int j  = v >> 4;
        const int c4 = (v & 15) << 2;
        const int t  = s0 - 7 + j;
        float4 m = make_float4(0.f, 0.f, 0.f, 0.f);
#pragma unroll
        for (int k = 0; k < Ldim; ++k) {
            const float w = w1[k];               // uniform -> s_load, hoisted
            const float4 xv = *(const float4*)(&xbuf[j + k][c4]);
            m.x = fmaf(w, xv.x, m.x);
            m.y = fmaf(w, xv.y, m.y);
            m.z = fmaf(w, xv.z, m.z);
            m.w = fmaf(w, xv.w, m.w);
        }
        const float4 xv = *(const float4*)(&xbuf[j + 7][c4]);
        float4 xc = make_float4(0.f, 0.f, 0.f, 0.f);
        if (t >= 0 && t < Tdim)
            xc = make_float4(xv.x - m.x, xv.y - m.y, xv.z - m.z, xv.w - m.w);
        *(float4*)(&xcs[j][c4]) = xc;
        if (j >= 7 && j <= 13 && ((j - 7) & 1) == 0)
            *(float4*)(&mus[(j - 7) >> 1][c4]) = m;   // always in-range (s0+2g < T)
    }
    __syncthreads();

    // ---- P3: shared-row Gram accumulation ----
    const int c0 = (tid >> 4) << 2;   // 0..60
    const int d0 = (tid & 15) << 2;   // 0..60
    float acc[G][4][4];
#pragma unroll
    for (int g = 0; g < G; ++g)
#pragma unroll
        for (int cc = 0; cc < 4; ++cc)
#pragma unroll
            for (int dd = 0; dd < 4; ++dd) acc[g][cc][dd] = 0.f;

#pragma unroll
    for (int r = 0; r < RXC; ++r) {
        const float4 xd = *(const float4*)(&xcs[r][d0]);   // ds_read_b128
        const float4 xc = *(const float4*)(&xcs[r][c0]);   // ds_read_b128 (bcast)
#pragma unroll
        for (int g = 0; g < G; ++g) {
            const int l = r - 2 * g;
            if (l >= 0 && l < Ldim) {                       // static after unroll
                const float w  = w2[l];                     // s_load, hoisted
                const float a0 = w * xc.x, a1 = w * xc.y, a2 = w * xc.z, a3 = w * xc.w;
                acc[g][0][0] = fmaf(a0, xd.x, acc[g][0][0]);
                acc[g][0][1] = fmaf(a0, xd.y, acc[g][0][1]);
                acc[g][0][2] = fmaf(a0, xd.z, acc[g][0][2]);
                acc[g][0][3] = fmaf(a0, xd.w, acc[g][0][3]);
                acc[g][1][0] = fmaf(a1, xd.x, acc[g][1][0]);
                acc[g][1][1] = fmaf(a1, xd.y, acc[g][1][1]);
                acc[g][1][2] = fmaf(a1, xd.z, acc[g][1][2]);
                acc[g][1][3] = fmaf(a1, xd.w, acc[g][1][3]);
                acc[g][2][0] = fmaf(a2, xd.x, acc[g][2][0]);
                acc[g][2][1] = fmaf(a2, xd.y, acc[g][2][1]);
                acc[g][2][2] = fmaf(a2, xd.z, acc[g][2][2]);
                acc[g][2][3] = fmaf(a2, xd.w, acc[g][2][3]);
                acc[g][3][0] = fmaf(a3, xd.x, acc[g][3][0]);
                acc[g][3][1] = fmaf(a3, xd.y, acc[g][3][1]);
                acc[g][3][2] = fmaf(a3, xd.z, acc[g][3][2]);
                acc[g][3][3] = fmaf(a3, xd.w, acc[g][3][3]);
            }
        }
    }

    // ---- P4: per-window sum of squares -> rsqrt scale ----
    float local[G];
#pragma unroll
    for (int g = 0; g < G; ++g) {
        float s = 0.f;
#pragma unroll
        for (int cc = 0; cc < 4; ++cc)
#pragma unroll
            for (int dd = 0; dd < 4; ++dd) s = fmaf(acc[g][cc][dd], acc[g][cc][dd], s);
        local[g] = s;
    }
    if (tid < Cdim) {
#pragma unroll
        for (int g = 0; g < G; ++g) local[g] = fmaf(mus[g][tid], mus[g][tid], local[g]);
    }
#pragma unroll
    for (int off = 32; off; off >>= 1)
#pragma unroll
        for (int g = 0; g < G; ++g) local[g] += __shfl_down(local[g], off, 64);
    if ((tid & 63) == 0) {
        const int w = tid >> 6;
#pragma unroll
        for (int g = 0; g < G; ++g) red[w][g] = local[g];
    }
    __syncthreads();
    if (tid < G) {
        const float ss = red[0][tid] + red[1][tid] + red[2][tid] + red[3][tid];
        scale_s[tid] = rsqrtf(fmaxf(ss, 1e-12f));
    }
    __syncthreads();

    // ---- Epilogue: coalesced stores ----
#pragma unroll
    for (int g = 0; g < G; ++g) {
        const float sc = scale_s[g];
        float* orow = out + (size_t)(b * Idim + i0 + g) * OUTW;
        if (tid < 16) {
            float4 m4 = *(const float4*)(&mus[g][tid << 2]);
            m4.x *= sc; m4.y *= sc; m4.z *= sc; m4.w *= sc;
            *(float4*)(orow + (tid << 2)) = m4;
        }
        float* osig = orow + Cdim;
#pragma unroll
        for (int cc = 0; cc < 4; ++cc) {
            const float4 v = make_float4(acc[g][cc][0] * sc, acc[g][cc][1] * sc,
                                         acc[g][cc][2] * sc, acc[g][cc][3] * sc);
            *(float4*)(osig + (c0 + cc) * Cdim + d0) = v;
        }
    }
}

extern "C" void kernel_launch(void* const* d_in, const int* in_sizes, int n_in,
                              void* d_out, int out_size, void* d_ws, size_t ws_size,
                              hipStream_t stream) {
    const float* x  = (const float*)d_in[0];
    const float* w1 = (const float*)d_in[1];
    const float* w2 = (const float*)d_in[2];
    float* out = (float*)d_out;
    cbp_kernel<<<dim3(Bdim * (Idim / G)), dim3(256), 0, stream>>>(x, w1, w2, out);
}